// Round 3
// baseline (417.705 us; speedup 1.0000x reference)
//
#include <hip/hip_runtime.h>
#include <stdint.h>

#define BATCH 8192
#define IN 4096
#define OUT 4096
#define EPS 1e-4f
#define RCHUNK 128
#define NCHUNKS (BATCH / RCHUNK)   // 64

typedef int v4i __attribute__((ext_vector_type(4)));
typedef unsigned char u8;

#define AS1(p) ((const __attribute__((address_space(1))) void*)(p))
#define AS3(p) ((__attribute__((address_space(3))) void*)(p))

// ---------------- Kernel 1: partial column sums (S1, S2), float4 ----------------
// NOTE: per-column add order identical to previous rounds (bit-identical stats).
__global__ __launch_bounds__(256) void colstat_partial(
    const float* __restrict__ x, float* __restrict__ P1, float* __restrict__ P2) {
    int c4 = blockIdx.x * 256 + threadIdx.x;   // float4 column index 0..1023
    int r0 = blockIdx.y * RCHUNK;
    float4 s1 = {0.f, 0.f, 0.f, 0.f}, s2 = {0.f, 0.f, 0.f, 0.f};
    const float4* p = (const float4*)x + (size_t)r0 * (IN / 4) + c4;
#pragma unroll 8
    for (int r = 0; r < RCHUNK; ++r) {
        float4 v = p[(size_t)r * (IN / 4)];
        s1.x += v.x; s1.y += v.y; s1.z += v.z; s1.w += v.w;
        s2.x += v.x * v.x; s2.y += v.y * v.y; s2.z += v.z * v.z; s2.w += v.w * v.w;
    }
    ((float4*)P1)[blockIdx.y * (IN / 4) + c4] = s1;
    ((float4*)P2)[blockIdx.y * (IN / 4) + c4] = s2;
}

// ---------------- Kernel 2: finalize mu, a = rstd*gamma ----------------
__global__ __launch_bounds__(256) void colstat_final(
    const float* __restrict__ P1, const float* __restrict__ P2,
    const float* __restrict__ gamma, float* __restrict__ mu, float* __restrict__ aArr) {
    int col = blockIdx.x * 256 + threadIdx.x;
    double s1 = 0.0, s2 = 0.0;
#pragma unroll 4
    for (int c = 0; c < NCHUNKS; ++c) {
        s1 += (double)P1[c * IN + col];
        s2 += (double)P2[c * IN + col];
    }
    double m = s1 / (double)BATCH;
    double var = s2 / (double)BATCH - m * m;
    float rstd = (float)(1.0 / sqrt(var + (double)EPS));
    mu[col] = (float)m;
    aArr[col] = rstd * gamma[col];
}

// ---------------- Kernel 3: fused binarize of weight (blocks 0..OUT-1) and x
// (blocks OUT..OUT+BATCH-1). Same per-block programs as before (bit-identical).
__global__ __launch_bounds__(256) void binxw(
    const float* __restrict__ x, const float* __restrict__ mu,
    const float* __restrict__ aArr, const float* __restrict__ beta,
    const float* __restrict__ w,
    u8* __restrict__ x01, int* __restrict__ px,
    u8* __restrict__ w01, float* __restrict__ scale, int* __restrict__ pw) {
    __shared__ double redd[4];
    __shared__ int redi[4];
    __shared__ double bcast;
    int tid = threadIdx.x;
    int lane = tid & 63;
    int wv = tid >> 6;

    if (blockIdx.x < OUT) {
        // ---- weight path ----
        int o = blockIdx.x;
        const float4* row = (const float4*)(w + (size_t)o * IN);
        uchar4* o4 = (uchar4*)(w01 + (size_t)o * IN);

        float4 vs[4];
        float part = 0.f;
#pragma unroll
        for (int it = 0; it < 4; ++it) {
            vs[it] = row[it * 256 + tid];
            part += vs[it].x + vs[it].y + vs[it].z + vs[it].w;
        }
        double d = (double)part;
        for (int off = 32; off > 0; off >>= 1) d += __shfl_down(d, off, 64);
        if (lane == 0) redd[wv] = d;
        __syncthreads();
        if (tid == 0) bcast = (redd[0] + redd[1] + redd[2] + redd[3]) / (double)IN;
        __syncthreads();
        float mean = (float)bcast;

        float absacc = 0.f;
        int cnt = 0;
#pragma unroll
        for (int it = 0; it < 4; ++it) {
            float4 v = vs[it];
            float wcx = v.x - mean, wcy = v.y - mean, wcz = v.z - mean, wcw = v.w - mean;
            uchar4 ob;
            ob.x = (u8)(wcx > 0.f);
            ob.y = (u8)(wcy > 0.f);
            ob.z = (u8)(wcz > 0.f);
            ob.w = (u8)(wcw > 0.f);
            cnt += (int)ob.x + (int)ob.y + (int)ob.z + (int)ob.w;
            absacc += fminf(fabsf(wcx), 1.0f) + fminf(fabsf(wcy), 1.0f) +
                      fminf(fabsf(wcz), 1.0f) + fminf(fabsf(wcw), 1.0f);
            o4[it * 256 + tid] = ob;
        }
        double da = (double)absacc;
        for (int off = 32; off > 0; off >>= 1) da += __shfl_down(da, off, 64);
        for (int off = 32; off > 0; off >>= 1) cnt += __shfl_down(cnt, off, 64);
        if (lane == 0) { redd[wv] = da; redi[wv] = cnt; }
        __syncthreads();
        if (tid == 0) {
            scale[o] = (float)((redd[0] + redd[1] + redd[2] + redd[3]) / (double)IN);
            pw[o] = redi[0] + redi[1] + redi[2] + redi[3];
        }
    } else {
        // ---- activation path ----
        int r = blockIdx.x - OUT;
        const float4* row = (const float4*)(x + (size_t)r * IN);
        const float4* m4 = (const float4*)mu;
        const float4* a4 = (const float4*)aArr;
        const float4* b4 = (const float4*)beta;
        uchar4* o4 = (uchar4*)(x01 + (size_t)r * IN);
        int cnt = 0;
#pragma unroll
        for (int it = 0; it < IN / 1024; ++it) {   // 4 iters
            int q = it * 256 + tid;
            float4 v = row[q];
            float4 m = m4[q];
            float4 a = a4[q];
            float4 b = b4[q];
            uchar4 ob;
            ob.x = (u8)((v.x - m.x) * a.x + b.x > 0.f);
            ob.y = (u8)((v.y - m.y) * a.y + b.y > 0.f);
            ob.z = (u8)((v.z - m.z) * a.z + b.z > 0.f);
            ob.w = (u8)((v.w - m.w) * a.w + b.w > 0.f);
            cnt += (int)ob.x + (int)ob.y + (int)ob.z + (int)ob.w;
            o4[q] = ob;
        }
        for (int off = 32; off > 0; off >>= 1) cnt += __shfl_down(cnt, off, 64);
        if (lane == 0) redi[wv] = cnt;
        __syncthreads();
        if (tid == 0) px[r] = redi[0] + redi[1] + redi[2] + redi[3];
    }
}

// ---------------- Kernel 4: i8 MFMA GEMM, 256x256 tile, 8-phase pipeline ----------------
// 8 waves (2M x 4N), per-wave 128x64 output = 8x4 frags of 16x16, BK=128 bytes.
// LDS 128 KiB: 2 bufs x (A 32K + B 32K). Even K-tiles -> buf0, odd -> buf1.
// Stage units = 64 rows x 128 B. Balanced 2 units/phase; counted vmcnt 10/4/6/2.
// Region-freedom: every STG slot >= 1 barrier after last read of old data.
// dot_{+-1} = 4*acc - 2*px[r] - 2*pw[c] + IN
#define BKB 128
#define NKT (IN / BKB)     // 32
#define NIT (NKT / 2)      // 16

#define STG_A(t, q, p) __builtin_amdgcn_global_load_lds( \
    AS1(ag + (size_t)((q)*64 + slr) * IN + (t)*BKB + sswz), \
    AS3(lds + (p)*65536 + (q)*8192 + sdst), 16, 0, 0)
#define STG_B(t, q, p) __builtin_amdgcn_global_load_lds( \
    AS1(bg + (size_t)((q)*64 + slr) * IN + (t)*BKB + sswz), \
    AS3(lds + (p)*65536 + 32768 + (q)*8192 + sdst), 16, 0, 0)

#define LOADA(p, rh) do { \
    _Pragma("unroll") for (int i_ = 0; i_ < 4; ++i_) \
    _Pragma("unroll") for (int k_ = 0; k_ < 2; ++k_) \
        af[i_][k_] = *(const v4i*)(lds + (p)*65536 + aBase + (rh)*8192 + i_*2048 + swk[k_]); \
} while (0)
#define LOADB(p, ch) do { \
    _Pragma("unroll") for (int j_ = 0; j_ < 2; ++j_) \
    _Pragma("unroll") for (int k_ = 0; k_ < 2; ++k_) \
        bf[j_][k_] = *(const v4i*)(lds + (p)*65536 + bBase + (ch)*4096 + j_*2048 + swk[k_]); \
} while (0)
#define MMA(rh, ch) do { \
    __builtin_amdgcn_s_setprio(1); \
    _Pragma("unroll") for (int i_ = 0; i_ < 4; ++i_) \
    _Pragma("unroll") for (int j_ = 0; j_ < 2; ++j_) \
    _Pragma("unroll") for (int k_ = 0; k_ < 2; ++k_) \
        acc[(rh)*4 + i_][(ch)*2 + j_] = __builtin_amdgcn_mfma_i32_16x16x64_i8( \
            af[i_][k_], bf[j_][k_], acc[(rh)*4 + i_][(ch)*2 + j_], 0, 0, 0); \
    __builtin_amdgcn_s_setprio(0); \
} while (0)
#define BAR() asm volatile("s_barrier" ::: "memory")
#define VM(n) asm volatile("s_waitcnt vmcnt(" #n ")" ::: "memory")

__global__ __launch_bounds__(512, 2) void bgemm_i8(
    const u8* __restrict__ x01, const u8* __restrict__ w01,
    const int* __restrict__ px, const int* __restrict__ pw,
    const float* __restrict__ scale, const float* __restrict__ bias,
    float* __restrict__ out) {
    __shared__ u8 lds[131072];

    int tid = threadIdx.x;
    int lane = tid & 63;
    int wave = tid >> 6;          // 0..7
    int wm = wave >> 2;           // 0..1  (row half)
    int wn = wave & 3;            // 0..3  (col quarter)

    // XCD-aware block swizzle (512 blocks, 512%8==0 -> bijective)
    int lin = blockIdx.y * (OUT / 256) + blockIdx.x;   // 0..511
    int swz = (lin & 7) * 64 + (lin >> 3);
    int colBlk = (swz & 15) * 256;
    int rowBlk = (swz >> 4) * 256;

    const u8* ag = x01 + (size_t)rowBlk * IN;
    const u8* bg = w01 + (size_t)colBlk * IN;

    // staging thread constants (linear LDS dest, inverse-swizzled global src)
    int slr = tid >> 3;                 // row within 64-row unit
    int ss = tid & 7;                   // 16B slot
    int sswz = (ss ^ (slr & 7)) * 16;   // swizzled source byte offset
    int sdst = slr * 128 + ss * 16;     // linear LDS byte offset within unit

    // ds_read thread constants
    int lrow = lane & 15;
    int lhi = lane >> 4;
    int llo = lane & 7;
    int swk[2] = { ((lhi) ^ llo) * 16, ((4 + lhi) ^ llo) * 16 };
    int aBase = (wm * 128 + lrow) * 128;
    int bBase = 32768 + (wn * 64 + lrow) * 128;

    v4i acc[8][4];
#pragma unroll
    for (int i = 0; i < 8; ++i)
#pragma unroll
        for (int j = 0; j < 4; ++j) acc[i][j] = (v4i){0, 0, 0, 0};
    v4i af[4][2], bf[2][2];

    // ---- prologue: emulate steady-state "prev iteration" staging order ----
    STG_A(0, 0, 0); STG_A(0, 2, 0);
    STG_A(0, 1, 0); STG_A(0, 3, 0);
    STG_B(0, 0, 0); STG_B(0, 1, 0);
    STG_B(0, 2, 0); STG_B(0, 3, 0);
    STG_A(1, 0, 1); STG_A(1, 2, 1);
    VM(2);
    BAR();

    // ---- steady iterations j=0..NIT-2: compute E=2j (buf0), O=2j+1 (buf1) ----
    for (int j = 0; j < NIT - 1; ++j) {
        int O = 2 * j + 1, E2 = 2 * j + 2, O2 = 2 * j + 3;
        // P1
        STG_B(O, 0, 1); STG_B(O, 1, 1);
        LOADA(0, 0); LOADB(0, 0);
        BAR(); MMA(0, 0); BAR();
        // P2
        STG_B(O, 2, 1); STG_B(O, 3, 1);
        LOADB(0, 1);
        BAR(); MMA(0, 1); VM(10); BAR();
        // P3
        STG_A(O, 1, 1); STG_A(O, 3, 1);
        LOADA(0, 1); LOADB(0, 0);
        BAR(); MMA(1, 0); BAR();
        // P4
        STG_A(E2, 0, 0); STG_A(E2, 2, 0);
        LOADB(0, 1);
        BAR(); MMA(1, 1); VM(4); BAR();
        // P5
        STG_A(E2, 1, 0); STG_A(E2, 3, 0);
        LOADA(1, 0); LOADB(1, 0);
        BAR(); MMA(0, 0); BAR();
        // P6
        STG_B(E2, 0, 0); STG_B(E2, 1, 0);
        LOADB(1, 1);
        BAR(); MMA(0, 1); VM(6); BAR();
        // P7
        STG_B(E2, 2, 0); STG_B(E2, 3, 0);
        LOADA(1, 1); LOADB(1, 0);
        BAR(); MMA(1, 0); BAR();
        // P8
        STG_A(O2, 0, 1); STG_A(O2, 2, 1);
        LOADB(1, 1);
        BAR(); MMA(1, 1); VM(2); BAR();
    }

    // ---- peeled last iteration: E=30 (buf0), O=31 (buf1) ----
    {
        int O = NKT - 1;   // 31
        // P1
        STG_B(O, 0, 1); STG_B(O, 1, 1);
        LOADA(0, 0); LOADB(0, 0);
        BAR(); MMA(0, 0); BAR();
        // P2
        STG_B(O, 2, 1); STG_B(O, 3, 1);
        LOADB(0, 1);
        BAR(); MMA(0, 1); VM(10); BAR();
        // P3
        STG_A(O, 1, 1); STG_A(O, 3, 1);
        LOADA(0, 1); LOADB(0, 0);
        BAR(); MMA(1, 0); BAR();
        // P4
        LOADB(0, 1);
        BAR(); MMA(1, 1); VM(2); BAR();
        // P5
        LOADA(1, 0); LOADB(1, 0);
        BAR(); MMA(0, 0); BAR();
        // P6
        LOADB(1, 1);
        BAR(); MMA(0, 1); VM(0); BAR();
        // P7
        LOADA(1, 1); LOADB(1, 0);
        BAR(); MMA(1, 0); BAR();
        // P8
        LOADB(1, 1);
        BAR(); MMA(1, 1); BAR();
    }

    // ---- epilogue (nontemporal stores: out is never re-read) ----
    int crow0 = lhi * 4;
    int ccol = lrow;
#pragma unroll
    for (int i = 0; i < 8; ++i) {
        int rbase = rowBlk + wm * 128 + i * 16 + crow0;
        int pxr[4];
#pragma unroll
        for (int rg = 0; rg < 4; ++rg) pxr[rg] = px[rbase + rg];
#pragma unroll
        for (int j = 0; j < 4; ++j) {
            int cb = colBlk + wn * 64 + j * 16 + ccol;
            float sc = scale[cb];
            float bs = bias[cb];
            int pwc = pw[cb];
#pragma unroll
            for (int rg = 0; rg < 4; ++rg) {
                int dot = 4 * acc[i][j][rg] - 2 * pxr[rg] - 2 * pwc + IN;
                float y = ((float)dot + bs) * sc;
                __builtin_nontemporal_store(y > 0.f ? y : 0.f,
                                            &out[(size_t)(rbase + rg) * OUT + cb]);
            }
        }
    }
}

extern "C" void kernel_launch(void* const* d_in, const int* in_sizes, int n_in,
                              void* d_out, int out_size, void* d_ws, size_t ws_size,
                              hipStream_t stream) {
    const float* x = (const float*)d_in[0];
    const float* gamma = (const float*)d_in[1];
    const float* beta = (const float*)d_in[2];
    const float* weight = (const float*)d_in[3];
    const float* bias = (const float*)d_in[4];
    float* out = (float*)d_out;

    char* w = (char*)d_ws;
    float* mu = (float*)(w);                    // 16 KB
    float* aArr = (float*)(w + 16384);          // 16 KB
    float* scale = (float*)(w + 32768);         // 16 KB
    int* px = (int*)(w + 49152);                // 32 KB
    int* pw = (int*)(w + 81920);                // 16 KB
    float* P1 = (float*)(w + (1 << 20));        // 1 MB
    float* P2 = (float*)(w + (2 << 20));        // 1 MB
    u8* x01 = (u8*)(w + (4 << 20));             // 32 MB
    u8* w01 = (u8*)(w + (36 << 20));            // 16 MB  (total 52 MB)

    colstat_partial<<<dim3(IN / 1024, NCHUNKS), 256, 0, stream>>>(x, P1, P2);
    colstat_final<<<dim3(IN / 256), 256, 0, stream>>>(P1, P2, gamma, mu, aArr);
    binxw<<<dim3(OUT + BATCH), 256, 0, stream>>>(x, mu, aArr, beta, weight,
                                                 x01, px, w01, scale, pw);
    bgemm_i8<<<dim3(OUT / 256, BATCH / 256), 512, 0, stream>>>(x01, w01, px, pw, scale, bias, out);
}

// Round 4
// 402.646 us; speedup vs baseline: 1.0374x; 1.0374x over previous
//
#include <hip/hip_runtime.h>
#include <stdint.h>

#define BATCH 8192
#define IN 4096
#define OUT 4096
#define EPS 1e-4f
#define RCHUNK 128
#define NCHUNKS (BATCH / RCHUNK)   // 64

typedef int v4i __attribute__((ext_vector_type(4)));
typedef unsigned char u8;

#define AS1(p) ((const __attribute__((address_space(1))) void*)(p))
#define AS3(p) ((__attribute__((address_space(3))) void*)(p))

// ---------------- Kernel 1: partial column sums (S1, S2), float4 ----------------
__global__ __launch_bounds__(256) void colstat_partial(
    const float* __restrict__ x, float* __restrict__ P1, float* __restrict__ P2) {
    int c4 = blockIdx.x * 256 + threadIdx.x;   // float4 column index 0..1023
    int r0 = blockIdx.y * RCHUNK;
    float4 s1 = {0.f, 0.f, 0.f, 0.f}, s2 = {0.f, 0.f, 0.f, 0.f};
    const float4* p = (const float4*)x + (size_t)r0 * (IN / 4) + c4;
#pragma unroll 8
    for (int r = 0; r < RCHUNK; ++r) {
        float4 v = p[(size_t)r * (IN / 4)];
        s1.x += v.x; s1.y += v.y; s1.z += v.z; s1.w += v.w;
        s2.x += v.x * v.x; s2.y += v.y * v.y; s2.z += v.z * v.z; s2.w += v.w * v.w;
    }
    ((float4*)P1)[blockIdx.y * (IN / 4) + c4] = s1;
    ((float4*)P2)[blockIdx.y * (IN / 4) + c4] = s2;
}

// ---------------- Kernel 2: finalize mu, a = rstd*gamma ----------------
__global__ __launch_bounds__(256) void colstat_final(
    const float* __restrict__ P1, const float* __restrict__ P2,
    const float* __restrict__ gamma, float* __restrict__ mu, float* __restrict__ aArr) {
    int col = blockIdx.x * 256 + threadIdx.x;
    double s1 = 0.0, s2 = 0.0;
#pragma unroll 4
    for (int c = 0; c < NCHUNKS; ++c) {
        s1 += (double)P1[c * IN + col];
        s2 += (double)P2[c * IN + col];
    }
    double m = s1 / (double)BATCH;
    double var = s2 / (double)BATCH - m * m;
    float rstd = (float)(1.0 / sqrt(var + (double)EPS));
    mu[col] = (float)m;
    aArr[col] = rstd * gamma[col];
}

// ---------------- Kernel 3: fused binarize of weight (blocks 0..OUT-1) and x
// (blocks OUT..OUT+BATCH-1). Bit-identical per-block programs.
__global__ __launch_bounds__(256) void binxw(
    const float* __restrict__ x, const float* __restrict__ mu,
    const float* __restrict__ aArr, const float* __restrict__ beta,
    const float* __restrict__ w,
    u8* __restrict__ x01, int* __restrict__ px,
    u8* __restrict__ w01, float* __restrict__ scale, int* __restrict__ pw) {
    __shared__ double redd[4];
    __shared__ int redi[4];
    __shared__ double bcast;
    int tid = threadIdx.x;
    int lane = tid & 63;
    int wv = tid >> 6;

    if (blockIdx.x < OUT) {
        // ---- weight path ----
        int o = blockIdx.x;
        const float4* row = (const float4*)(w + (size_t)o * IN);
        uchar4* o4 = (uchar4*)(w01 + (size_t)o * IN);

        float4 vs[4];
        float part = 0.f;
#pragma unroll
        for (int it = 0; it < 4; ++it) {
            vs[it] = row[it * 256 + tid];
            part += vs[it].x + vs[it].y + vs[it].z + vs[it].w;
        }
        double d = (double)part;
        for (int off = 32; off > 0; off >>= 1) d += __shfl_down(d, off, 64);
        if (lane == 0) redd[wv] = d;
        __syncthreads();
        if (tid == 0) bcast = (redd[0] + redd[1] + redd[2] + redd[3]) / (double)IN;
        __syncthreads();
        float mean = (float)bcast;

        float absacc = 0.f;
        int cnt = 0;
#pragma unroll
        for (int it = 0; it < 4; ++it) {
            float4 v = vs[it];
            float wcx = v.x - mean, wcy = v.y - mean, wcz = v.z - mean, wcw = v.w - mean;
            uchar4 ob;
            ob.x = (u8)(wcx > 0.f);
            ob.y = (u8)(wcy > 0.f);
            ob.z = (u8)(wcz > 0.f);
            ob.w = (u8)(wcw > 0.f);
            cnt += (int)ob.x + (int)ob.y + (int)ob.z + (int)ob.w;
            absacc += fminf(fabsf(wcx), 1.0f) + fminf(fabsf(wcy), 1.0f) +
                      fminf(fabsf(wcz), 1.0f) + fminf(fabsf(wcw), 1.0f);
            o4[it * 256 + tid] = ob;
        }
        double da = (double)absacc;
        for (int off = 32; off > 0; off >>= 1) da += __shfl_down(da, off, 64);
        for (int off = 32; off > 0; off >>= 1) cnt += __shfl_down(cnt, off, 64);
        if (lane == 0) { redd[wv] = da; redi[wv] = cnt; }
        __syncthreads();
        if (tid == 0) {
            scale[o] = (float)((redd[0] + redd[1] + redd[2] + redd[3]) / (double)IN);
            pw[o] = redi[0] + redi[1] + redi[2] + redi[3];
        }
    } else {
        // ---- activation path ----
        int r = blockIdx.x - OUT;
        const float4* row = (const float4*)(x + (size_t)r * IN);
        const float4* m4 = (const float4*)mu;
        const float4* a4 = (const float4*)aArr;
        const float4* b4 = (const float4*)beta;
        uchar4* o4 = (uchar4*)(x01 + (size_t)r * IN);
        int cnt = 0;
#pragma unroll
        for (int it = 0; it < IN / 1024; ++it) {   // 4 iters
            int q = it * 256 + tid;
            float4 v = row[q];
            float4 m = m4[q];
            float4 a = a4[q];
            float4 b = b4[q];
            uchar4 ob;
            ob.x = (u8)((v.x - m.x) * a.x + b.x > 0.f);
            ob.y = (u8)((v.y - m.y) * a.y + b.y > 0.f);
            ob.z = (u8)((v.z - m.z) * a.z + b.z > 0.f);
            ob.w = (u8)((v.w - m.w) * a.w + b.w > 0.f);
            cnt += (int)ob.x + (int)ob.y + (int)ob.z + (int)ob.w;
            o4[q] = ob;
        }
        for (int off = 32; off > 0; off >>= 1) cnt += __shfl_down(cnt, off, 64);
        if (lane == 0) redi[wv] = cnt;
        __syncthreads();
        if (tid == 0) px[r] = redi[0] + redi[1] + redi[2] + redi[3];
    }
}

// ---------------- Kernel 4: i8 MFMA GEMM, 256x256 tile, 8-phase pipeline ----------------
// R2-proven skeleton (staging layout, VM counts, prologue, plain stores) with ONE change:
// B-fragment register reuse. bf0 (ch0) loaded in P1, consumed in P1 and P3;
// bf1 (ch1) loaded in P2, consumed in P2 and P4. Cuts ds_read_b128 per wave per
// K-tile from 32 to 24 (-25% LDS read traffic) -> LDS stream drops below MFMA floor.
// dot_{+-1} = 4*acc - 2*px[r] - 2*pw[c] + IN
#define BKB 128
#define NKT (IN / BKB)     // 32
#define NIT (NKT / 2)      // 16

#define STG_A(t, q, p) __builtin_amdgcn_global_load_lds( \
    AS1(ag + (size_t)((q)*64 + slr) * IN + (t)*BKB + sswz), \
    AS3(lds + (p)*65536 + (q)*8192 + sdst), 16, 0, 0)
#define STG_B(t, q, p) __builtin_amdgcn_global_load_lds( \
    AS1(bg + (size_t)((q)*64 + slr) * IN + (t)*BKB + sswz), \
    AS3(lds + (p)*65536 + 32768 + (q)*8192 + sdst), 16, 0, 0)

#define LOADA(p, rh) do { \
    _Pragma("unroll") for (int i_ = 0; i_ < 4; ++i_) \
    _Pragma("unroll") for (int k_ = 0; k_ < 2; ++k_) \
        af[i_][k_] = *(const v4i*)(lds + (p)*65536 + aBase + (rh)*8192 + i_*2048 + swk[k_]); \
} while (0)
#define LOADB(p, ch, arr) do { \
    _Pragma("unroll") for (int j_ = 0; j_ < 2; ++j_) \
    _Pragma("unroll") for (int k_ = 0; k_ < 2; ++k_) \
        arr[j_][k_] = *(const v4i*)(lds + (p)*65536 + bBase + (ch)*4096 + j_*2048 + swk[k_]); \
} while (0)
#define MMA(rh, ch, arr) do { \
    __builtin_amdgcn_s_setprio(1); \
    _Pragma("unroll") for (int i_ = 0; i_ < 4; ++i_) \
    _Pragma("unroll") for (int j_ = 0; j_ < 2; ++j_) \
    _Pragma("unroll") for (int k_ = 0; k_ < 2; ++k_) \
        acc[(rh)*4 + i_][(ch)*2 + j_] = __builtin_amdgcn_mfma_i32_16x16x64_i8( \
            af[i_][k_], arr[j_][k_], acc[(rh)*4 + i_][(ch)*2 + j_], 0, 0, 0); \
    __builtin_amdgcn_s_setprio(0); \
} while (0)
#define BAR() asm volatile("s_barrier" ::: "memory")
#define VM(n) asm volatile("s_waitcnt vmcnt(" #n ")" ::: "memory")

__global__ __launch_bounds__(512, 2) void bgemm_i8(
    const u8* __restrict__ x01, const u8* __restrict__ w01,
    const int* __restrict__ px, const int* __restrict__ pw,
    const float* __restrict__ scale, const float* __restrict__ bias,
    float* __restrict__ out) {
    __shared__ u8 lds[131072];

    int tid = threadIdx.x;
    int lane = tid & 63;
    int wave = tid >> 6;          // 0..7
    int wm = wave >> 2;           // 0..1  (row half)
    int wn = wave & 3;            // 0..3  (col quarter)

    // XCD-aware block swizzle (512 blocks, 512%8==0 -> bijective)
    int lin = blockIdx.y * (OUT / 256) + blockIdx.x;   // 0..511
    int swz = (lin & 7) * 64 + (lin >> 3);
    int colBlk = (swz & 15) * 256;
    int rowBlk = (swz >> 4) * 256;

    const u8* ag = x01 + (size_t)rowBlk * IN;
    const u8* bg = w01 + (size_t)colBlk * IN;

    // staging thread constants (linear LDS dest, inverse-swizzled global src)
    int slr = tid >> 3;                 // row within 64-row unit
    int ss = tid & 7;                   // 16B slot
    int sswz = (ss ^ (slr & 7)) * 16;   // swizzled source byte offset
    int sdst = slr * 128 + ss * 16;     // linear LDS byte offset within unit

    // ds_read thread constants
    int lrow = lane & 15;
    int lhi = lane >> 4;
    int llo = lane & 7;
    int swk[2] = { ((lhi) ^ llo) * 16, ((4 + lhi) ^ llo) * 16 };
    int aBase = (wm * 128 + lrow) * 128;
    int bBase = 32768 + (wn * 64 + lrow) * 128;

    v4i acc[8][4];
#pragma unroll
    for (int i = 0; i < 8; ++i)
#pragma unroll
        for (int j = 0; j < 4; ++j) acc[i][j] = (v4i){0, 0, 0, 0};
    v4i af[4][2], bf0[2][2], bf1[2][2];

    // ---- prologue: tile0 fully (8 units), tile1 A units 0,2 ----
    STG_A(0, 0, 0); STG_A(0, 1, 0); STG_A(0, 2, 0); STG_A(0, 3, 0);
    STG_B(0, 0, 0); STG_B(0, 1, 0); STG_B(0, 2, 0); STG_B(0, 3, 0);
    STG_A(1, 0, 1); STG_A(1, 2, 1);
    VM(2);
    BAR();

    // ---- steady iterations j=0..NIT-2: compute E=2j (buf0), O=2j+1 (buf1) ----
    for (int j = 0; j < NIT - 1; ++j) {
        int O = 2 * j + 1, E2 = 2 * j + 2, O2 = 2 * j + 3;
        // P1: E (rh0,ch0)
        LOADA(0, 0); LOADB(0, 0, bf0);
        STG_B(O, 0, 1); STG_B(O, 1, 1);
        BAR(); MMA(0, 0, bf0); BAR();
        // P2: (rh0,ch1)
        LOADB(0, 1, bf1);
        STG_B(O, 2, 1); STG_B(O, 3, 1);
        BAR(); MMA(0, 1, bf1); VM(6); BAR();
        // P3: (rh1,ch0) -- bf0 reused from P1
        LOADA(0, 1);
        STG_A(O, 1, 1); STG_A(O, 3, 1); STG_A(E2, 0, 0); STG_A(E2, 2, 0);
        BAR(); MMA(1, 0, bf0); BAR();
        // P4: (rh1,ch1) -- bf1 reused from P2
        BAR(); MMA(1, 1, bf1); VM(4); BAR();
        // P5: O (rh0,ch0)
        LOADA(1, 0); LOADB(1, 0, bf0);
        STG_B(E2, 0, 0); STG_B(E2, 1, 0);
        BAR(); MMA(0, 0, bf0); BAR();
        // P6: (rh0,ch1)
        LOADB(1, 1, bf1);
        STG_B(E2, 2, 0); STG_B(E2, 3, 0);
        BAR(); MMA(0, 1, bf1); VM(4); BAR();
        // P7: (rh1,ch0)
        LOADA(1, 1);
        STG_A(E2, 1, 0); STG_A(E2, 3, 0);
        BAR(); MMA(1, 0, bf0); BAR();
        // P8: (rh1,ch1)
        STG_A(O2, 0, 1); STG_A(O2, 2, 1);
        BAR(); MMA(1, 1, bf1); VM(4); BAR();
    }

    // ---- peeled last iteration: E=30 (buf0), O=31 (buf1) ----
    {
        int O = NKT - 1;   // 31
        // P1
        LOADA(0, 0); LOADB(0, 0, bf0);
        STG_B(O, 0, 1); STG_B(O, 1, 1);
        BAR(); MMA(0, 0, bf0); BAR();
        // P2
        LOADB(0, 1, bf1);
        STG_B(O, 2, 1); STG_B(O, 3, 1);
        BAR(); MMA(0, 1, bf1); VM(6); BAR();
        // P3
        LOADA(0, 1);
        STG_A(O, 1, 1); STG_A(O, 3, 1);
        BAR(); MMA(1, 0, bf0); BAR();
        // P4
        BAR(); MMA(1, 1, bf1); VM(2); BAR();
        // P5
        LOADA(1, 0); LOADB(1, 0, bf0);
        BAR(); MMA(0, 0, bf0); BAR();
        // P6
        LOADB(1, 1, bf1);
        BAR(); MMA(0, 1, bf1); VM(0); BAR();
        // P7
        LOADA(1, 1);
        BAR(); MMA(1, 0, bf0); BAR();
        // P8
        BAR(); MMA(1, 1, bf1); BAR();
    }

    // ---- epilogue (plain stores; NT stores caused write amplification) ----
    int crow0 = lhi * 4;
    int ccol = lrow;
#pragma unroll
    for (int i = 0; i < 8; ++i) {
        int rbase = rowBlk + wm * 128 + i * 16 + crow0;
        int pxr[4];
#pragma unroll
        for (int rg = 0; rg < 4; ++rg) pxr[rg] = px[rbase + rg];
#pragma unroll
        for (int j = 0; j < 4; ++j) {
            int cb = colBlk + wn * 64 + j * 16 + ccol;
            float sc = scale[cb];
            float bs = bias[cb];
            int pwc = pw[cb];
#pragma unroll
            for (int rg = 0; rg < 4; ++rg) {
                int dot = 4 * acc[i][j][rg] - 2 * pxr[rg] - 2 * pwc + IN;
                float y = ((float)dot + bs) * sc;
                out[(size_t)(rbase + rg) * OUT + cb] = y > 0.f ? y : 0.f;
            }
        }
    }
}

extern "C" void kernel_launch(void* const* d_in, const int* in_sizes, int n_in,
                              void* d_out, int out_size, void* d_ws, size_t ws_size,
                              hipStream_t stream) {
    const float* x = (const float*)d_in[0];
    const float* gamma = (const float*)d_in[1];
    const float* beta = (const float*)d_in[2];
    const float* weight = (const float*)d_in[3];
    const float* bias = (const float*)d_in[4];
    float* out = (float*)d_out;

    char* w = (char*)d_ws;
    float* mu = (float*)(w);                    // 16 KB
    float* aArr = (float*)(w + 16384);          // 16 KB
    float* scale = (float*)(w + 32768);         // 16 KB
    int* px = (int*)(w + 49152);                // 32 KB
    int* pw = (int*)(w + 81920);                // 16 KB
    float* P1 = (float*)(w + (1 << 20));        // 1 MB
    float* P2 = (float*)(w + (2 << 20));        // 1 MB
    u8* x01 = (u8*)(w + (4 << 20));             // 32 MB
    u8* w01 = (u8*)(w + (36 << 20));            // 16 MB  (total 52 MB)

    colstat_partial<<<dim3(IN / 1024, NCHUNKS), 256, 0, stream>>>(x, P1, P2);
    colstat_final<<<dim3(IN / 256), 256, 0, stream>>>(P1, P2, gamma, mu, aArr);
    binxw<<<dim3(OUT + BATCH), 256, 0, stream>>>(x, mu, aArr, beta, weight,
                                                 x01, px, w01, scale, pw);
    bgemm_i8<<<dim3(OUT / 256, BATCH / 256), 512, 0, stream>>>(x01, w01, px, pw, scale, bias, out);
}

// Round 5
// 400.701 us; speedup vs baseline: 1.0424x; 1.0049x over previous
//
#include <hip/hip_runtime.h>
#include <stdint.h>

#define BATCH 8192
#define IN 4096
#define OUT 4096
#define EPS 1e-4f
#define RCHUNK 128
#define NCHUNKS (BATCH / RCHUNK)   // 64

typedef int v4i __attribute__((ext_vector_type(4)));
typedef unsigned char u8;

#define AS1(p) ((const __attribute__((address_space(1))) void*)(p))
#define AS3(p) ((__attribute__((address_space(3))) void*)(p))

// ---------------- Kernel 1: partial column sums (S1, S2), float4 ----------------
__global__ __launch_bounds__(256) void colstat_partial(
    const float* __restrict__ x, float* __restrict__ P1, float* __restrict__ P2) {
    int c4 = blockIdx.x * 256 + threadIdx.x;   // float4 column index 0..1023
    int r0 = blockIdx.y * RCHUNK;
    float4 s1 = {0.f, 0.f, 0.f, 0.f}, s2 = {0.f, 0.f, 0.f, 0.f};
    const float4* p = (const float4*)x + (size_t)r0 * (IN / 4) + c4;
#pragma unroll 8
    for (int r = 0; r < RCHUNK; ++r) {
        float4 v = p[(size_t)r * (IN / 4)];
        s1.x += v.x; s1.y += v.y; s1.z += v.z; s1.w += v.w;
        s2.x += v.x * v.x; s2.y += v.y * v.y; s2.z += v.z * v.z; s2.w += v.w * v.w;
    }
    ((float4*)P1)[blockIdx.y * (IN / 4) + c4] = s1;
    ((float4*)P2)[blockIdx.y * (IN / 4) + c4] = s2;
}

// ---------------- Kernel 2: finalize mu, a = rstd*gamma ----------------
__global__ __launch_bounds__(256) void colstat_final(
    const float* __restrict__ P1, const float* __restrict__ P2,
    const float* __restrict__ gamma, float* __restrict__ mu, float* __restrict__ aArr) {
    int col = blockIdx.x * 256 + threadIdx.x;
    double s1 = 0.0, s2 = 0.0;
#pragma unroll 4
    for (int c = 0; c < NCHUNKS; ++c) {
        s1 += (double)P1[c * IN + col];
        s2 += (double)P2[c * IN + col];
    }
    double m = s1 / (double)BATCH;
    double var = s2 / (double)BATCH - m * m;
    float rstd = (float)(1.0 / sqrt(var + (double)EPS));
    mu[col] = (float)m;
    aArr[col] = rstd * gamma[col];
}

// ---------------- Kernel 3: fused binarize of weight (blocks 0..OUT-1) and x
// (blocks OUT..OUT+BATCH-1). Bit-identical per-block programs.
__global__ __launch_bounds__(256) void binxw(
    const float* __restrict__ x, const float* __restrict__ mu,
    const float* __restrict__ aArr, const float* __restrict__ beta,
    const float* __restrict__ w,
    u8* __restrict__ x01, int* __restrict__ px,
    u8* __restrict__ w01, float* __restrict__ scale, int* __restrict__ pw) {
    __shared__ double redd[4];
    __shared__ int redi[4];
    __shared__ double bcast;
    int tid = threadIdx.x;
    int lane = tid & 63;
    int wv = tid >> 6;

    if (blockIdx.x < OUT) {
        // ---- weight path ----
        int o = blockIdx.x;
        const float4* row = (const float4*)(w + (size_t)o * IN);
        uchar4* o4 = (uchar4*)(w01 + (size_t)o * IN);

        float4 vs[4];
        float part = 0.f;
#pragma unroll
        for (int it = 0; it < 4; ++it) {
            vs[it] = row[it * 256 + tid];
            part += vs[it].x + vs[it].y + vs[it].z + vs[it].w;
        }
        double d = (double)part;
        for (int off = 32; off > 0; off >>= 1) d += __shfl_down(d, off, 64);
        if (lane == 0) redd[wv] = d;
        __syncthreads();
        if (tid == 0) bcast = (redd[0] + redd[1] + redd[2] + redd[3]) / (double)IN;
        __syncthreads();
        float mean = (float)bcast;

        float absacc = 0.f;
        int cnt = 0;
#pragma unroll
        for (int it = 0; it < 4; ++it) {
            float4 v = vs[it];
            float wcx = v.x - mean, wcy = v.y - mean, wcz = v.z - mean, wcw = v.w - mean;
            uchar4 ob;
            ob.x = (u8)(wcx > 0.f);
            ob.y = (u8)(wcy > 0.f);
            ob.z = (u8)(wcz > 0.f);
            ob.w = (u8)(wcw > 0.f);
            cnt += (int)ob.x + (int)ob.y + (int)ob.z + (int)ob.w;
            absacc += fminf(fabsf(wcx), 1.0f) + fminf(fabsf(wcy), 1.0f) +
                      fminf(fabsf(wcz), 1.0f) + fminf(fabsf(wcw), 1.0f);
            o4[it * 256 + tid] = ob;
        }
        double da = (double)absacc;
        for (int off = 32; off > 0; off >>= 1) da += __shfl_down(da, off, 64);
        for (int off = 32; off > 0; off >>= 1) cnt += __shfl_down(cnt, off, 64);
        if (lane == 0) { redd[wv] = da; redi[wv] = cnt; }
        __syncthreads();
        if (tid == 0) {
            scale[o] = (float)((redd[0] + redd[1] + redd[2] + redd[3]) / (double)IN);
            pw[o] = redi[0] + redi[1] + redi[2] + redi[3];
        }
    } else {
        // ---- activation path ----
        int r = blockIdx.x - OUT;
        const float4* row = (const float4*)(x + (size_t)r * IN);
        const float4* m4 = (const float4*)mu;
        const float4* a4 = (const float4*)aArr;
        const float4* b4 = (const float4*)beta;
        uchar4* o4 = (uchar4*)(x01 + (size_t)r * IN);
        int cnt = 0;
#pragma unroll
        for (int it = 0; it < IN / 1024; ++it) {   // 4 iters
            int q = it * 256 + tid;
            float4 v = row[q];
            float4 m = m4[q];
            float4 a = a4[q];
            float4 b = b4[q];
            uchar4 ob;
            ob.x = (u8)((v.x - m.x) * a.x + b.x > 0.f);
            ob.y = (u8)((v.y - m.y) * a.y + b.y > 0.f);
            ob.z = (u8)((v.z - m.z) * a.z + b.z > 0.f);
            ob.w = (u8)((v.w - m.w) * a.w + b.w > 0.f);
            cnt += (int)ob.x + (int)ob.y + (int)ob.z + (int)ob.w;
            o4[q] = ob;
        }
        for (int off = 32; off > 0; off >>= 1) cnt += __shfl_down(cnt, off, 64);
        if (lane == 0) redi[wv] = cnt;
        __syncthreads();
        if (tid == 0) px[r] = redi[0] + redi[1] + redi[2] + redi[3];
    }
}

// ---------------- Kernel 4: i8 MFMA GEMM, 256x256 tile, 8-phase, deep pipeline ----
// Change vs R4: STG units moved to the EARLIEST region-free phase (tile E2 staged
// P2/P3/P4, tile O2 staged P6/P7/P8), giving each unit >=5 phases of flight.
// Counted vmcnt ladder recomputed: VM(8)@P2, VM(10)@P4, VM(8)@P6, VM(10)@P8.
// Issue ledger per iter: P2:a0,a2(E2) P3:b0..b3(E2) P4:a1,a3(E2)
//                        P6:a0,a2(O2) P7:b0..b3(O2) P8:a1,a3(O2)  (16/iter)
// Read points need completion through: prev-P3 (at P1), prev-P4 (at P3),
// prev-P7 (at P5), prev-P8 (at P7) -> outstanding-allowed 10/8/10/8, waits
// placed at end of the preceding phase (VM; BAR; reads) so all waves' loads
// are covered before any wave's ds_read. Region-freedom: every STG >=1 barrier
// after the consuming phase's BAR2. B-frag register reuse kept (bf0:P1+P3,
// bf1:P2+P4). dot_{+-1} = 4*acc - 2*px[r] - 2*pw[c] + IN
#define BKB 128
#define NKT (IN / BKB)     // 32
#define NIT (NKT / 2)      // 16

#define STG_A(t, q, p) __builtin_amdgcn_global_load_lds( \
    AS1(ag + (size_t)((q)*64 + slr) * IN + (t)*BKB + sswz), \
    AS3(lds + (p)*65536 + (q)*8192 + sdst), 16, 0, 0)
#define STG_B(t, q, p) __builtin_amdgcn_global_load_lds( \
    AS1(bg + (size_t)((q)*64 + slr) * IN + (t)*BKB + sswz), \
    AS3(lds + (p)*65536 + 32768 + (q)*8192 + sdst), 16, 0, 0)

#define LOADA(p, rh) do { \
    _Pragma("unroll") for (int i_ = 0; i_ < 4; ++i_) \
    _Pragma("unroll") for (int k_ = 0; k_ < 2; ++k_) \
        af[i_][k_] = *(const v4i*)(lds + (p)*65536 + aBase + (rh)*8192 + i_*2048 + swk[k_]); \
} while (0)
#define LOADB(p, ch, arr) do { \
    _Pragma("unroll") for (int j_ = 0; j_ < 2; ++j_) \
    _Pragma("unroll") for (int k_ = 0; k_ < 2; ++k_) \
        arr[j_][k_] = *(const v4i*)(lds + (p)*65536 + bBase + (ch)*4096 + j_*2048 + swk[k_]); \
} while (0)
#define MMA(rh, ch, arr) do { \
    __builtin_amdgcn_s_setprio(1); \
    _Pragma("unroll") for (int i_ = 0; i_ < 4; ++i_) \
    _Pragma("unroll") for (int j_ = 0; j_ < 2; ++j_) \
    _Pragma("unroll") for (int k_ = 0; k_ < 2; ++k_) \
        acc[(rh)*4 + i_][(ch)*2 + j_] = __builtin_amdgcn_mfma_i32_16x16x64_i8( \
            af[i_][k_], arr[j_][k_], acc[(rh)*4 + i_][(ch)*2 + j_], 0, 0, 0); \
    __builtin_amdgcn_s_setprio(0); \
} while (0)
#define BAR() asm volatile("s_barrier" ::: "memory")
#define VM(n) asm volatile("s_waitcnt vmcnt(" #n ")" ::: "memory")

__global__ __launch_bounds__(512, 2) void bgemm_i8(
    const u8* __restrict__ x01, const u8* __restrict__ w01,
    const int* __restrict__ px, const int* __restrict__ pw,
    const float* __restrict__ scale, const float* __restrict__ bias,
    float* __restrict__ out) {
    __shared__ u8 lds[131072];

    int tid = threadIdx.x;
    int lane = tid & 63;
    int wave = tid >> 6;          // 0..7
    int wm = wave >> 2;           // 0..1  (row half)
    int wn = wave & 3;            // 0..3  (col quarter)

    // XCD-aware block swizzle (512 blocks, 512%8==0 -> bijective)
    int lin = blockIdx.y * (OUT / 256) + blockIdx.x;   // 0..511
    int swz = (lin & 7) * 64 + (lin >> 3);
    int colBlk = (swz & 15) * 256;
    int rowBlk = (swz >> 4) * 256;

    const u8* ag = x01 + (size_t)rowBlk * IN;
    const u8* bg = w01 + (size_t)colBlk * IN;

    // staging thread constants (linear LDS dest, inverse-swizzled global src)
    int slr = tid >> 3;                 // row within 64-row unit
    int ss = tid & 7;                   // 16B slot
    int sswz = (ss ^ (slr & 7)) * 16;   // swizzled source byte offset
    int sdst = slr * 128 + ss * 16;     // linear LDS byte offset within unit

    // ds_read thread constants
    int lrow = lane & 15;
    int lhi = lane >> 4;
    int llo = lane & 7;
    int swk[2] = { ((lhi) ^ llo) * 16, ((4 + lhi) ^ llo) * 16 };
    int aBase = (wm * 128 + lrow) * 128;
    int bBase = 32768 + (wn * 64 + lrow) * 128;

    v4i acc[8][4];
#pragma unroll
    for (int i = 0; i < 8; ++i)
#pragma unroll
        for (int j = 0; j < 4; ++j) acc[i][j] = (v4i){0, 0, 0, 0};
    v4i af[4][2], bf0[2][2], bf1[2][2];

    // ---- prologue: stage tile0 (buf0) and tile1 (buf1) fully, in the
    // steady-state issue order (a0,a2,b0..b3,a1,a3 per tile). ----
    STG_A(0, 0, 0); STG_A(0, 2, 0);
    STG_B(0, 0, 0); STG_B(0, 1, 0); STG_B(0, 2, 0); STG_B(0, 3, 0);
    STG_A(0, 1, 0); STG_A(0, 3, 0);
    STG_A(1, 0, 1); STG_A(1, 2, 1);
    STG_B(1, 0, 1); STG_B(1, 1, 1); STG_B(1, 2, 1); STG_B(1, 3, 1);
    STG_A(1, 1, 1); STG_A(1, 3, 1);
    VM(10);   // complete through tile0's b3 (load #6); 10 younger in flight
    BAR();

    // ---- steady iterations j=0..NIT-2: compute E=2j (buf0), O=2j+1 (buf1) ----
    for (int j = 0; j < NIT - 1; ++j) {
        int E2 = 2 * j + 2, O2 = 2 * j + 3;
        // P1: E (rh0,ch0)
        LOADA(0, 0); LOADB(0, 0, bf0);
        BAR(); MMA(0, 0, bf0); BAR();
        // P2: (rh0,ch1); stage E2 a0,a2 (A0/A2 free after P1)
        LOADB(0, 1, bf1);
        STG_A(E2, 0, 0); STG_A(E2, 2, 0);
        BAR(); MMA(0, 1, bf1); VM(8); BAR();
        // P3: (rh1,ch0) bf0 reused; stage E2 b0..b3 (B units free after P2)
        LOADA(0, 1);
        STG_B(E2, 0, 0); STG_B(E2, 1, 0); STG_B(E2, 2, 0); STG_B(E2, 3, 0);
        BAR(); MMA(1, 0, bf0); BAR();
        // P4: (rh1,ch1) bf1 reused; stage E2 a1,a3 (A1/A3 free after P3)
        STG_A(E2, 1, 0); STG_A(E2, 3, 0);
        BAR(); MMA(1, 1, bf1); VM(10); BAR();
        // P5: O (rh0,ch0)
        LOADA(1, 0); LOADB(1, 0, bf0);
        BAR(); MMA(0, 0, bf0); BAR();
        // P6: (rh0,ch1); stage O2 a0,a2
        LOADB(1, 1, bf1);
        STG_A(O2, 0, 1); STG_A(O2, 2, 1);
        BAR(); MMA(0, 1, bf1); VM(8); BAR();
        // P7: (rh1,ch0) bf0 reused; stage O2 b0..b3
        LOADA(1, 1);
        STG_B(O2, 0, 1); STG_B(O2, 1, 1); STG_B(O2, 2, 1); STG_B(O2, 3, 1);
        BAR(); MMA(1, 0, bf0); BAR();
        // P8: (rh1,ch1) bf1 reused; stage O2 a1,a3
        STG_A(O2, 1, 1); STG_A(O2, 3, 1);
        BAR(); MMA(1, 1, bf1); VM(10); BAR();
    }

    // ---- peeled last iteration: E=30 (buf0), O=31 (buf1); no staging ----
    {
        // P1
        LOADA(0, 0); LOADB(0, 0, bf0);
        BAR(); MMA(0, 0, bf0); BAR();
        // P2
        LOADB(0, 1, bf1);
        BAR(); MMA(0, 1, bf1); VM(8); BAR();
        // P3
        LOADA(0, 1);
        BAR(); MMA(1, 0, bf0); BAR();
        // P4
        BAR(); MMA(1, 1, bf1); VM(2); BAR();
        // P5
        LOADA(1, 0); LOADB(1, 0, bf0);
        BAR(); MMA(0, 0, bf0); BAR();
        // P6
        LOADB(1, 1, bf1);
        BAR(); MMA(0, 1, bf1); VM(0); BAR();
        // P7
        LOADA(1, 1);
        BAR(); MMA(1, 0, bf0); BAR();
        // P8
        BAR(); MMA(1, 1, bf1); BAR();
    }

    // ---- epilogue (plain stores; NT stores caused write amplification) ----
    int crow0 = lhi * 4;
    int ccol = lrow;
#pragma unroll
    for (int i = 0; i < 8; ++i) {
        int rbase = rowBlk + wm * 128 + i * 16 + crow0;
        int pxr[4];
#pragma unroll
        for (int rg = 0; rg < 4; ++rg) pxr[rg] = px[rbase + rg];
#pragma unroll
        for (int j = 0; j < 4; ++j) {
            int cb = colBlk + wn * 64 + j * 16 + ccol;
            float sc = scale[cb];
            float bs = bias[cb];
            int pwc = pw[cb];
#pragma unroll
            for (int rg = 0; rg < 4; ++rg) {
                int dot = 4 * acc[i][j][rg] - 2 * pxr[rg] - 2 * pwc + IN;
                float y = ((float)dot + bs) * sc;
                out[(size_t)(rbase + rg) * OUT + cb] = y > 0.f ? y : 0.f;
            }
        }
    }
}

extern "C" void kernel_launch(void* const* d_in, const int* in_sizes, int n_in,
                              void* d_out, int out_size, void* d_ws, size_t ws_size,
                              hipStream_t stream) {
    const float* x = (const float*)d_in[0];
    const float* gamma = (const float*)d_in[1];
    const float* beta = (const float*)d_in[2];
    const float* weight = (const float*)d_in[3];
    const float* bias = (const float*)d_in[4];
    float* out = (float*)d_out;

    char* w = (char*)d_ws;
    float* mu = (float*)(w);                    // 16 KB
    float* aArr = (float*)(w + 16384);          // 16 KB
    float* scale = (float*)(w + 32768);         // 16 KB
    int* px = (int*)(w + 49152);                // 32 KB
    int* pw = (int*)(w + 81920);                // 16 KB
    float* P1 = (float*)(w + (1 << 20));        // 1 MB
    float* P2 = (float*)(w + (2 << 20));        // 1 MB
    u8* x01 = (u8*)(w + (4 << 20));             // 32 MB
    u8* w01 = (u8*)(w + (36 << 20));            // 16 MB  (total 52 MB)

    colstat_partial<<<dim3(IN / 1024, NCHUNKS), 256, 0, stream>>>(x, P1, P2);
    colstat_final<<<dim3(IN / 256), 256, 0, stream>>>(P1, P2, gamma, mu, aArr);
    binxw<<<dim3(OUT + BATCH), 256, 0, stream>>>(x, mu, aArr, beta, weight,
                                                 x01, px, w01, scale, pw);
    bgemm_i8<<<dim3(OUT / 256, BATCH / 256), 512, 0, stream>>>(x01, w01, px, pw, scale, bias, out);
}